// Round 11
// baseline (1022.587 us; speedup 1.0000x reference)
//
#include <hip/hip_runtime.h>
#include <hip/hip_bf16.h>
#include <hip/hip_fp16.h>

#define N_NODES 100000
#define E_EDGES 1250000
#define INC 64
#define HIDC 128
#define OUTC 64
#define K_ITERS 10
#define ALPHA 0.1f

typedef _Float16 f16x8 __attribute__((ext_vector_type(8)));
typedef float f32x4 __attribute__((ext_vector_type(4)));
typedef float f32x2 __attribute__((ext_vector_type(2)));
typedef int i32x2 __attribute__((ext_vector_type(2)));

// ---------------------------------------------------------------------------
// histograms: degRow[ei0]++ (enhancement CSR), degDst[ei1]++ (APPNP CSR)
// ei is a read-once stream -> non-temporal loads (keep L2 for gather sets)
// ---------------------------------------------------------------------------
__global__ __launch_bounds__(256) void hist2(const int* __restrict__ ei,
                                             int* __restrict__ degRow,
                                             int* __restrict__ degDst) {
    int e = blockIdx.x * 256 + threadIdx.x;
    if (e >= E_EDGES) return;
    int r0 = __builtin_nontemporal_load(ei + e);
    int r1 = __builtin_nontemporal_load(ei + E_EDGES + e);
    atomicAdd(&degRow[r0], 1);
    atomicAdd(&degDst[r1], 1);
}

// ---------------------------------------------------------------------------
// dinv = rsqrt(degDst+1)   (deg includes self loop)
// ---------------------------------------------------------------------------
__global__ __launch_bounds__(256) void dinv_kernel(const int* __restrict__ degDst,
                                                   float* __restrict__ dinv) {
    int i = blockIdx.x * 256 + threadIdx.x;
    if (i >= N_NODES) return;
    dinv[i] = rsqrtf((float)(degDst[i] + 1));
}

// ---------------------------------------------------------------------------
// x -> fp16 copy (for the random-gather path; self-term still reads fp32 x)
// ---------------------------------------------------------------------------
__global__ __launch_bounds__(256) void xconvert(const float2* __restrict__ x2,
                                                __half2* __restrict__ x16) {
    int i = blockIdx.x * 256 + threadIdx.x;
    if (i >= N_NODES * 32) return;
    float2 v = x2[i];
    x16[i] = __floats2half2_rn(v.x, v.y);
}

// ---------------------------------------------------------------------------
// W -> fp16 TRANSPOSED copy: dst[n][k] = W[k][n] (k<64 from Wa, else Wb if set)
// ---------------------------------------------------------------------------
__global__ __launch_bounds__(256) void wtrans(const float* __restrict__ Wa,
                                              const float* __restrict__ Wb,
                                              __half* __restrict__ dst, int NC) {
    int idx = blockIdx.x * 256 + threadIdx.x;
    if (idx >= NC * 128) return;
    int n = idx >> 7, k = idx & 127;
    float v;
    if (Wb != nullptr && k >= 64) v = Wb[(size_t)(k - 64) * NC + n];
    else v = Wa[(size_t)k * NC + n];
    dst[idx] = __float2half(v);
}

// ---------------------------------------------------------------------------
// fused 2-array exclusive scan -> rpRow, rpDst
// ---------------------------------------------------------------------------
__global__ __launch_bounds__(256) void scan_block_sums2(const int* __restrict__ degRow,
                                                        const int* __restrict__ degDst,
                                                        int* __restrict__ blockSums) {
    const int* deg = blockIdx.y ? degDst : degRow;
    __shared__ int sh[256];
    int t = threadIdx.x;
    int i = blockIdx.x * 256 + t;
    sh[t] = (i < N_NODES) ? deg[i] : 0;
    __syncthreads();
    for (int off = 128; off > 0; off >>= 1) {
        if (t < off) sh[t] += sh[t + off];
        __syncthreads();
    }
    if (t == 0) blockSums[blockIdx.y * 512 + blockIdx.x] = sh[0];
}

__global__ __launch_bounds__(512) void scan_top2(const int* __restrict__ blockSums,
                                                 int* __restrict__ blockScan, int nb) {
    const int* bs = blockSums + blockIdx.x * 512;
    int* bo = blockScan + blockIdx.x * 512;
    __shared__ int sh[512];
    int t = threadIdx.x;
    int v = (t < nb) ? bs[t] : 0;
    sh[t] = v;
    __syncthreads();
    for (int off = 1; off < 512; off <<= 1) {
        int xv = (t >= off) ? sh[t - off] : 0;
        __syncthreads();
        sh[t] += xv;
        __syncthreads();
    }
    if (t < nb) bo[t] = sh[t] - v;  // exclusive
}

__global__ __launch_bounds__(256) void scan_write_rp2(const int* __restrict__ degRow,
                                                      const int* __restrict__ degDst,
                                                      const int* __restrict__ blockScan,
                                                      int* __restrict__ rpRow,
                                                      int* __restrict__ rpDst) {
    const int* deg = blockIdx.y ? degDst : degRow;
    int* rp = blockIdx.y ? rpDst : rpRow;
    __shared__ int sh[256];
    int t = threadIdx.x;
    int i = blockIdx.x * 256 + t;
    int v = (i < N_NODES) ? deg[i] : 0;
    sh[t] = v;
    __syncthreads();
    for (int off = 1; off < 256; off <<= 1) {
        int xv = (t >= off) ? sh[t - off] : 0;
        __syncthreads();
        sh[t] += xv;
        __syncthreads();
    }
    if (i < N_NODES) rp[i] = blockScan[blockIdx.y * 512 + blockIdx.x] + (sh[t] - v);
    if (i == 0) rp[N_NODES] = E_EDGES;
}

// ---------------------------------------------------------------------------
// scatter into BOTH CSRs (packed payloads):
//  enhancement CSR (key=ei0): ce[pos] = (col, edge_id)
//  APPNP CSR       (key=ei1): ew[pos] = (src, 0.9*dinv[src]*dinv[dst])
// NT: ei stream loads; scattered payload stores (no write-allocate)
// ---------------------------------------------------------------------------
__global__ __launch_bounds__(256) void scatter_both(const int* __restrict__ ei,
                                                    const float* __restrict__ dinv,
                                                    const int* __restrict__ rpRow,
                                                    const int* __restrict__ rpDst,
                                                    int* __restrict__ curRow,
                                                    int* __restrict__ curDst,
                                                    int2* __restrict__ ce,
                                                    int2* __restrict__ ew) {
    int e = blockIdx.x * 256 + threadIdx.x;
    if (e >= E_EDGES) return;
    int r0 = __builtin_nontemporal_load(ei + e);            // row / src
    int r1 = __builtin_nontemporal_load(ei + E_EDGES + e);  // col / dst
    int pr = rpRow[r0] + atomicAdd(&curRow[r0], 1);
    i32x2 cv; cv.x = r1; cv.y = e;
    __builtin_nontemporal_store(cv, (i32x2*)&ce[pr]);
    int pd = rpDst[r1] + atomicAdd(&curDst[r1], 1);
    float w = (1.0f - ALPHA) * dinv[r0] * dinv[r1];
    i32x2 wv; wv.x = r0; wv.y = __float_as_int(w);
    __builtin_nontemporal_store(wv, (i32x2*)&ew[pd]);
}

// ---------------------------------------------------------------------------
// aggregate (gather, no atomics): one wave per node; half-wave h processes
// edges j+h; x gathered fp16; output S fp16.
// NT: ce payload loads, ea stream loads (read-once 320MB), S16 stores.
// ---------------------------------------------------------------------------
__global__ __launch_bounds__(256) void aggregate(const float2* __restrict__ x2,
                                                 const __half2* __restrict__ x16,
                                                 const float2* __restrict__ ea2,
                                                 const int* __restrict__ rpRow,
                                                 const int2* __restrict__ ce,
                                                 __half2* __restrict__ S16,
                                                 float* __restrict__ cntRow) {
    int wid = (blockIdx.x * 256 + threadIdx.x) >> 6;
    int lane = threadIdx.x & 63;
    if (wid >= N_NODES) return;
    int half = lane >> 5;
    int l2 = lane & 31;
    int jb = rpRow[wid], je = rpRow[wid + 1];
    float ax0 = 0.f, ay0 = 0.f, ax1 = 0.f, ay1 = 0.f;
    float ex0 = 0.f, ey0 = 0.f, ex1 = 0.f, ey1 = 0.f;
    if (!half) {
        float2 self = x2[(size_t)wid * 32 + l2];  // exact fp32 self term
        ax0 = self.x; ay0 = self.y;
    }
    int j = jb;
    for (; j + 3 < je; j += 4) {
        i32x2 c0 = __builtin_nontemporal_load((const i32x2*)&ce[j + half]);
        i32x2 c1 = __builtin_nontemporal_load((const i32x2*)&ce[j + 2 + half]);
        float2 xg0 = __half22float2(x16[(size_t)c0.x * 32 + l2]);
        f32x2 eg0 = __builtin_nontemporal_load((const f32x2*)&ea2[(size_t)c0.y * 32 + l2]);
        float2 xg1 = __half22float2(x16[(size_t)c1.x * 32 + l2]);
        f32x2 eg1 = __builtin_nontemporal_load((const f32x2*)&ea2[(size_t)c1.y * 32 + l2]);
        ax0 += xg0.x; ay0 += xg0.y; ex0 += eg0.x; ey0 += eg0.y;
        ax1 += xg1.x; ay1 += xg1.y; ex1 += eg1.x; ey1 += eg1.y;
    }
    for (; j < je; j += 2) {
        int ii = j + half;
        i32x2 c = __builtin_nontemporal_load((const i32x2*)&ce[ii < je ? ii : (je - 1)]);
        float m = (ii < je) ? 1.0f : 0.0f;
        float2 xg = __half22float2(x16[(size_t)c.x * 32 + l2]);
        f32x2 eg = __builtin_nontemporal_load((const f32x2*)&ea2[(size_t)c.y * 32 + l2]);
        ax0 += m * xg.x; ay0 += m * xg.y;
        ex0 += m * eg.x; ey0 += m * eg.y;
    }
    ax0 += ax1; ay0 += ay1; ex0 += ex1; ey0 += ey1;
    ax0 += __shfl_xor(ax0, 32);
    ay0 += __shfl_xor(ay0, 32);
    ex0 += __shfl_xor(ex0, 32);
    ey0 += __shfl_xor(ey0, 32);
    if (!half) {
        __half2 sa = __floats2half2_rn(ax0, ay0);
        __half2 se = __floats2half2_rn(ex0, ey0);
        __builtin_nontemporal_store(*(const unsigned int*)&sa,
                                    (unsigned int*)&S16[(size_t)wid * 64 + l2]);
        __builtin_nontemporal_store(*(const unsigned int*)&se,
                                    (unsigned int*)&S16[(size_t)wid * 64 + 32 + l2]);
        if (lane == 0) cntRow[wid] = (float)(je - jb + 1);
    }
}

// ---------------------------------------------------------------------------
// MFMA fp16 GEMM (unchanged from R10): out = epilogue(A[N,128] @ W[128,NC])
// ---------------------------------------------------------------------------
template <int NC, int MODE>
__global__ __launch_bounds__(256) void gemm_mfma(const __half* __restrict__ A,
                                                 const __half* __restrict__ Wt,
                                                 const float* __restrict__ ba,
                                                 const float* __restrict__ bb,
                                                 const float* __restrict__ cnt,
                                                 __half* __restrict__ out) {
    constexpr int NT = NC / 16;
    __shared__ __half Ah[64][136];
    __shared__ __half Wl[NC][136];
    const int tid = threadIdx.x;
    const int rb = blockIdx.x * 64;
    const int lane = tid & 63;
    const int wv = tid >> 6;    // wave 0..3, owns rows rb+wv*16 ..+16
    const int l15 = lane & 15;
    const int lb = lane >> 4;   // 0..3

    for (int idx = tid; idx < 64 * 16; idx += 256) {
        int r = idx >> 4, c8 = idx & 15;
        int gr = rb + r;
        uint4 v = make_uint4(0, 0, 0, 0);
        if (gr < N_NODES) v = *reinterpret_cast<const uint4*>(A + (size_t)gr * 128 + c8 * 8);
        *reinterpret_cast<uint4*>(&Ah[r][c8 * 8]) = v;
    }
    for (int idx = tid; idx < NC * 16; idx += 256) {
        int n = idx >> 4, c8 = idx & 15;
        uint4 v = *reinterpret_cast<const uint4*>(Wt + (size_t)n * 128 + c8 * 8);
        *reinterpret_cast<uint4*>(&Wl[n][c8 * 8]) = v;
    }
    __syncthreads();

    f16x8 af[4];
#pragma unroll
    for (int kc = 0; kc < 4; kc++)
        af[kc] = *reinterpret_cast<const f16x8*>(&Ah[wv * 16 + l15][kc * 32 + lb * 8]);

    f32x4 acc[NT];
#pragma unroll
    for (int nt = 0; nt < NT; nt++) acc[nt] = (f32x4){0.f, 0.f, 0.f, 0.f};

#pragma unroll
    for (int nt = 0; nt < NT; nt++) {
#pragma unroll
        for (int kc = 0; kc < 4; kc++) {
            f16x8 bf = *reinterpret_cast<const f16x8*>(&Wl[nt * 16 + l15][kc * 32 + lb * 8]);
            acc[nt] = __builtin_amdgcn_mfma_f32_16x16x32_f16(af[kc], bf, acc[nt], 0, 0, 0);
        }
    }

#pragma unroll
    for (int nt = 0; nt < NT; nt++) {
        int c = nt * 16 + l15;
        float bav = ba[c];
        float bbv = 0.f;
        if constexpr (MODE == 0) bbv = bb[c];
#pragma unroll
        for (int reg = 0; reg < 4; reg++) {
            int gr = rb + wv * 16 + lb * 4 + reg;
            if (gr >= N_NODES) continue;
            float v = acc[nt][reg];
            if constexpr (MODE == 0) {
                float inv = 1.0f / cnt[gr];
                v = v * inv + bav + (1.0f - inv) * bbv;
                v = fmaxf(v, 0.f);
            } else if constexpr (MODE == 1) {
                v = fmaxf(v + bav, 0.f);
            } else {
                v = v + bav;
            }
            out[(size_t)gr * NC + c] = __float2half(v);
        }
    }
}

// ---------------------------------------------------------------------------
// APPNP step: out[n] = 0.9*dinv^2*h[n] + sum w'*h[src] + 0.1*h0[n]
// NT on out stores (write-allocate buys nothing: next-iter readers are on
// other XCDs); gather loads stay cached.
// ---------------------------------------------------------------------------
template <bool LAST>
__global__ __launch_bounds__(256) void appnp_step(const __half2* __restrict__ h2,
                                                  const __half2* __restrict__ h02,
                                                  void* __restrict__ outv,
                                                  const int* __restrict__ rp,
                                                  const int2* __restrict__ ew,
                                                  const float* __restrict__ dinv) {
    int wid = (blockIdx.x * 256 + threadIdx.x) >> 6;
    int lane = threadIdx.x & 63;
    if (wid >= N_NODES) return;
    int half = lane >> 5;
    int l2 = lane & 31;
    float acc0x = 0.f, acc0y = 0.f, acc1x = 0.f, acc1y = 0.f;
    if (!half) {
        float di = dinv[wid];
        float sw = (1.0f - ALPHA) * di * di;
        float2 hv = __half22float2(h2[(size_t)wid * 32 + l2]);
        acc0x = sw * hv.x; acc0y = sw * hv.y;
    }
    int e = rp[wid], eend = rp[wid + 1];
    for (; e + 3 < eend; e += 4) {
        int2 p0 = ew[e + half];
        int2 p1 = ew[e + 2 + half];
        float w0 = __int_as_float(p0.y);
        float w1 = __int_as_float(p1.y);
        float2 g0 = __half22float2(h2[(size_t)p0.x * 32 + l2]);
        float2 g1 = __half22float2(h2[(size_t)p1.x * 32 + l2]);
        acc0x += w0 * g0.x; acc0y += w0 * g0.y;
        acc1x += w1 * g1.x; acc1y += w1 * g1.y;
    }
    for (; e < eend; e += 2) {
        int ii = e + half;
        int2 p = ew[ii < eend ? ii : (eend - 1)];
        float w0 = (ii < eend) ? __int_as_float(p.y) : 0.0f;
        float2 g = __half22float2(h2[(size_t)p.x * 32 + l2]);
        acc0x += w0 * g.x; acc0y += w0 * g.y;
    }
    acc0x += acc1x; acc0y += acc1y;
    acc0x += __shfl_xor(acc0x, 32);
    acc0y += __shfl_xor(acc0y, 32);
    if (!half) {
        float2 hz = __half22float2(h02[(size_t)wid * 32 + l2]);
        float ox = acc0x + ALPHA * hz.x;
        float oy = acc0y + ALPHA * hz.y;
        if constexpr (LAST) {
            f32x2 o; o.x = ox; o.y = oy;
            __builtin_nontemporal_store(o, (f32x2*)&((float2*)outv)[(size_t)wid * 32 + l2]);
        } else {
            __half2 oh = __floats2half2_rn(ox, oy);
            __builtin_nontemporal_store(*(const unsigned int*)&oh,
                                        (unsigned int*)&((__half2*)outv)[(size_t)wid * 32 + l2]);
        }
    }
}

// ---------------------------------------------------------------------------
extern "C" void kernel_launch(void* const* d_in, const int* in_sizes, int n_in,
                              void* d_out, int out_size, void* d_ws, size_t ws_size,
                              hipStream_t stream) {
    const float* x      = (const float*)d_in[0];
    const float* eattr  = (const float*)d_in[1];
    const float* W_node = (const float*)d_in[2];
    const float* b_node = (const float*)d_in[3];
    const float* W_edge = (const float*)d_in[4];
    const float* b_edge = (const float*)d_in[5];
    const float* W1     = (const float*)d_in[6];
    const float* b1     = (const float*)d_in[7];
    const float* W2     = (const float*)d_in[8];
    const float* b2     = (const float*)d_in[9];
    const int*   ei     = (const int*)d_in[10];
    float* out = (float*)d_out;

    char* ws = (char*)d_ws;
    size_t off = 0;
    auto alloc = [&](size_t bytes) -> void* {
        void* p = ws + off;
        off += (bytes + 511) & ~(size_t)511;
        return p;
    };
    float*  buf0   = (float*)alloc((size_t)N_NODES * 128 * 4);   // S16; later hA16|hB16
    __half* h0_16  = (__half*)alloc((size_t)N_NODES * 64 * 2);   // also hosts ce early
    __half* x16    = (__half*)alloc((size_t)N_NODES * 64 * 2);
    int2*   ew     = (int2*)alloc((size_t)E_EDGES * 8);
    float*  cntRow = (float*)alloc((size_t)N_NODES * 4);
    int*    zeros4 = (int*)alloc((size_t)4 * N_NODES * 4);       // degRow|degDst|curRow|curDst
    float*  dinv   = (float*)alloc((size_t)N_NODES * 4);
    int*    rpRow  = (int*)alloc((size_t)(N_NODES + 1) * 4);
    int*    rpDst  = (int*)alloc((size_t)(N_NODES + 1) * 4);
    int*    blockSums = (int*)alloc(1024 * 4);
    int*    blockScan = (int*)alloc(1024 * 4);
    __half* wt0    = (__half*)alloc((size_t)128 * 128 * 2);      // [W_node;W_edge]^T fp16
    __half* wt1    = (__half*)alloc((size_t)128 * 128 * 2);      // W1^T fp16
    __half* wt2    = (__half*)alloc((size_t)64 * 128 * 2);       // W2^T fp16

    int* degRow = zeros4;
    int* degDst = zeros4 + N_NODES;
    int* curRow = zeros4 + 2 * N_NODES;
    int* curDst = zeros4 + 3 * N_NODES;

    // ce aliases the h0_16 region: dead before h0_16 is written (gemm_mfma<64,2>)
    int2* ce = (int2*)h0_16;
    __half* S16 = (__half*)buf0;

    constexpr int NB = (N_NODES + 255) / 256;  // 391 scan chunks (< 512)

    hipMemsetAsync(zeros4, 0, (size_t)4 * N_NODES * 4, stream);

    hist2<<<(E_EDGES + 255) / 256, 256, 0, stream>>>(ei, degRow, degDst);
    dinv_kernel<<<(N_NODES + 255) / 256, 256, 0, stream>>>(degDst, dinv);
    xconvert<<<(N_NODES * 32 + 255) / 256, 256, 0, stream>>>((const float2*)x, (__half2*)x16);
    wtrans<<<64, 256, 0, stream>>>(W_node, W_edge, wt0, 128);
    wtrans<<<64, 256, 0, stream>>>(W1, nullptr, wt1, 128);
    wtrans<<<32, 256, 0, stream>>>(W2, nullptr, wt2, 64);

    scan_block_sums2<<<dim3(NB, 2), 256, 0, stream>>>(degRow, degDst, blockSums);
    scan_top2<<<2, 512, 0, stream>>>(blockSums, blockScan, NB);
    scan_write_rp2<<<dim3(NB, 2), 256, 0, stream>>>(degRow, degDst, blockScan, rpRow, rpDst);

    scatter_both<<<(E_EDGES + 255) / 256, 256, 0, stream>>>(ei, dinv, rpRow, rpDst,
                                                            curRow, curDst, ce, ew);

    aggregate<<<(N_NODES + 3) / 4, 256, 0, stream>>>((const float2*)x, (const __half2*)x16,
                                                     (const float2*)eattr, rpRow, ce,
                                                     (__half2*)S16, cntRow);

    constexpr int GB = (N_NODES + 63) / 64;  // 1563 blocks
    gemm_mfma<128, 0><<<GB, 256, 0, stream>>>(S16, wt0, b_node, b_edge, cntRow, S16);
    gemm_mfma<128, 1><<<GB, 256, 0, stream>>>(S16, wt1, b1, nullptr, nullptr, S16);
    gemm_mfma<64, 2><<<GB, 256, 0, stream>>>(S16, wt2, b2, nullptr, nullptr, h0_16);

    // fp16 h double-buffers carved from buf0 (S16 dead after the GEMMs)
    __half2* hA16 = (__half2*)buf0;
    __half2* hB16 = (__half2*)(buf0 + (size_t)N_NODES * 32);  // +12.8MB
    const __half2* hcur = (const __half2*)h0_16;
    for (int k = 0; k < K_ITERS; k++) {
        if (k == K_ITERS - 1) {
            appnp_step<true><<<(N_NODES * 64 + 255) / 256, 256, 0, stream>>>(
                hcur, (const __half2*)h0_16, (void*)out, rpDst, ew, dinv);
        } else {
            __half2* dst = (k & 1) ? hB16 : hA16;
            appnp_step<false><<<(N_NODES * 64 + 255) / 256, 256, 0, stream>>>(
                hcur, (const __half2*)h0_16, (void*)dst, rpDst, ew, dinv);
            hcur = (const __half2*)dst;
        }
    }
}

// Round 12
// 990.003 us; speedup vs baseline: 1.0329x; 1.0329x over previous
//
#include <hip/hip_runtime.h>
#include <hip/hip_bf16.h>
#include <hip/hip_fp16.h>

#define N_NODES 100000
#define E_EDGES 1250000
#define INC 64
#define HIDC 128
#define OUTC 64
#define K_ITERS 10
#define ALPHA 0.1f

typedef _Float16 f16x8 __attribute__((ext_vector_type(8)));
typedef float f32x4 __attribute__((ext_vector_type(4)));

// ---------------------------------------------------------------------------
// histograms: degRow[ei0]++ (enhancement CSR), degDst[ei1]++ (APPNP CSR)
// ---------------------------------------------------------------------------
__global__ __launch_bounds__(256) void hist2(const int* __restrict__ ei,
                                             int* __restrict__ degRow,
                                             int* __restrict__ degDst) {
    int e = blockIdx.x * 256 + threadIdx.x;
    if (e >= E_EDGES) return;
    atomicAdd(&degRow[ei[e]], 1);
    atomicAdd(&degDst[ei[E_EDGES + e]], 1);
}

// ---------------------------------------------------------------------------
// dinv = rsqrt(degDst+1)   (deg includes self loop)
// ---------------------------------------------------------------------------
__global__ __launch_bounds__(256) void dinv_kernel(const int* __restrict__ degDst,
                                                   float* __restrict__ dinv) {
    int i = blockIdx.x * 256 + threadIdx.x;
    if (i >= N_NODES) return;
    dinv[i] = rsqrtf((float)(degDst[i] + 1));
}

// ---------------------------------------------------------------------------
// x -> fp16 copy (for the random-gather path; self-term still reads fp32 x)
// ---------------------------------------------------------------------------
__global__ __launch_bounds__(256) void xconvert(const float2* __restrict__ x2,
                                                __half2* __restrict__ x16) {
    int i = blockIdx.x * 256 + threadIdx.x;
    if (i >= N_NODES * 32) return;
    float2 v = x2[i];
    x16[i] = __floats2half2_rn(v.x, v.y);
}

// ---------------------------------------------------------------------------
// W -> fp16 TRANSPOSED copy: dst[n][k] = W[k][n] (k<64 from Wa, else Wb if set)
// dst pitch = 128 halves. Tiny one-time pass so MFMA B-frags are 16B-contiguous.
// ---------------------------------------------------------------------------
__global__ __launch_bounds__(256) void wtrans(const float* __restrict__ Wa,
                                              const float* __restrict__ Wb,
                                              __half* __restrict__ dst, int NC) {
    int idx = blockIdx.x * 256 + threadIdx.x;
    if (idx >= NC * 128) return;
    int n = idx >> 7, k = idx & 127;
    float v;
    if (Wb != nullptr && k >= 64) v = Wb[(size_t)(k - 64) * NC + n];
    else v = Wa[(size_t)k * NC + n];
    dst[idx] = __float2half(v);
}

// ---------------------------------------------------------------------------
// fused 2-array exclusive scan -> rpRow, rpDst
// ---------------------------------------------------------------------------
__global__ __launch_bounds__(256) void scan_block_sums2(const int* __restrict__ degRow,
                                                        const int* __restrict__ degDst,
                                                        int* __restrict__ blockSums) {
    const int* deg = blockIdx.y ? degDst : degRow;
    __shared__ int sh[256];
    int t = threadIdx.x;
    int i = blockIdx.x * 256 + t;
    sh[t] = (i < N_NODES) ? deg[i] : 0;
    __syncthreads();
    for (int off = 128; off > 0; off >>= 1) {
        if (t < off) sh[t] += sh[t + off];
        __syncthreads();
    }
    if (t == 0) blockSums[blockIdx.y * 512 + blockIdx.x] = sh[0];
}

__global__ __launch_bounds__(512) void scan_top2(const int* __restrict__ blockSums,
                                                 int* __restrict__ blockScan, int nb) {
    const int* bs = blockSums + blockIdx.x * 512;
    int* bo = blockScan + blockIdx.x * 512;
    __shared__ int sh[512];
    int t = threadIdx.x;
    int v = (t < nb) ? bs[t] : 0;
    sh[t] = v;
    __syncthreads();
    for (int off = 1; off < 512; off <<= 1) {
        int xv = (t >= off) ? sh[t - off] : 0;
        __syncthreads();
        sh[t] += xv;
        __syncthreads();
    }
    if (t < nb) bo[t] = sh[t] - v;  // exclusive
}

__global__ __launch_bounds__(256) void scan_write_rp2(const int* __restrict__ degRow,
                                                      const int* __restrict__ degDst,
                                                      const int* __restrict__ blockScan,
                                                      int* __restrict__ rpRow,
                                                      int* __restrict__ rpDst) {
    const int* deg = blockIdx.y ? degDst : degRow;
    int* rp = blockIdx.y ? rpDst : rpRow;
    __shared__ int sh[256];
    int t = threadIdx.x;
    int i = blockIdx.x * 256 + t;
    int v = (i < N_NODES) ? deg[i] : 0;
    sh[t] = v;
    __syncthreads();
    for (int off = 1; off < 256; off <<= 1) {
        int xv = (t >= off) ? sh[t - off] : 0;
        __syncthreads();
        sh[t] += xv;
        __syncthreads();
    }
    if (i < N_NODES) rp[i] = blockScan[blockIdx.y * 512 + blockIdx.x] + (sh[t] - v);
    if (i == 0) rp[N_NODES] = E_EDGES;
}

// ---------------------------------------------------------------------------
// scatter into BOTH CSRs (packed payloads):
//  enhancement CSR (key=ei0): ce[pos] = (col, edge_id)
//  APPNP CSR       (key=ei1): ew[pos] = (src, 0.9*dinv[src]*dinv[dst])
// ---------------------------------------------------------------------------
__global__ __launch_bounds__(256) void scatter_both(const int* __restrict__ ei,
                                                    const float* __restrict__ dinv,
                                                    const int* __restrict__ rpRow,
                                                    const int* __restrict__ rpDst,
                                                    int* __restrict__ curRow,
                                                    int* __restrict__ curDst,
                                                    int2* __restrict__ ce,
                                                    int2* __restrict__ ew) {
    int e = blockIdx.x * 256 + threadIdx.x;
    if (e >= E_EDGES) return;
    int r0 = ei[e];            // row / src
    int r1 = ei[E_EDGES + e];  // col / dst
    int pr = rpRow[r0] + atomicAdd(&curRow[r0], 1);
    ce[pr] = make_int2(r1, e);
    int pd = rpDst[r1] + atomicAdd(&curDst[r1], 1);
    float w = (1.0f - ALPHA) * dinv[r0] * dinv[r1];
    ew[pd] = make_int2(r0, __float_as_int(w));
}

// ---------------------------------------------------------------------------
// aggregate (gather, no atomics): one wave per node; half-wave h processes
// edges j+h; x gathered fp16; output S in fp16 (feeds MFMA GEMM).
// ---------------------------------------------------------------------------
__global__ __launch_bounds__(256) void aggregate(const float2* __restrict__ x2,
                                                 const __half2* __restrict__ x16,
                                                 const float2* __restrict__ ea2,
                                                 const int* __restrict__ rpRow,
                                                 const int2* __restrict__ ce,
                                                 __half2* __restrict__ S16,
                                                 float* __restrict__ cntRow) {
    int wid = (blockIdx.x * 256 + threadIdx.x) >> 6;
    int lane = threadIdx.x & 63;
    if (wid >= N_NODES) return;
    int half = lane >> 5;
    int l2 = lane & 31;
    int jb = rpRow[wid], je = rpRow[wid + 1];
    float ax0 = 0.f, ay0 = 0.f, ax1 = 0.f, ay1 = 0.f;
    float ex0 = 0.f, ey0 = 0.f, ex1 = 0.f, ey1 = 0.f;
    if (!half) {
        float2 self = x2[(size_t)wid * 32 + l2];  // exact fp32 self term
        ax0 = self.x; ay0 = self.y;
    }
    int j = jb;
    for (; j + 3 < je; j += 4) {
        int2 c0 = ce[j + half];
        int2 c1 = ce[j + 2 + half];
        float2 xg0 = __half22float2(x16[(size_t)c0.x * 32 + l2]);
        float2 eg0 = ea2[(size_t)c0.y * 32 + l2];
        float2 xg1 = __half22float2(x16[(size_t)c1.x * 32 + l2]);
        float2 eg1 = ea2[(size_t)c1.y * 32 + l2];
        ax0 += xg0.x; ay0 += xg0.y; ex0 += eg0.x; ey0 += eg0.y;
        ax1 += xg1.x; ay1 += xg1.y; ex1 += eg1.x; ey1 += eg1.y;
    }
    for (; j < je; j += 2) {
        int ii = j + half;
        int2 c = ce[ii < je ? ii : (je - 1)];
        float m = (ii < je) ? 1.0f : 0.0f;
        float2 xg = __half22float2(x16[(size_t)c.x * 32 + l2]);
        float2 eg = ea2[(size_t)c.y * 32 + l2];
        ax0 += m * xg.x; ay0 += m * xg.y;
        ex0 += m * eg.x; ey0 += m * eg.y;
    }
    ax0 += ax1; ay0 += ay1; ex0 += ex1; ey0 += ey1;
    ax0 += __shfl_xor(ax0, 32);
    ay0 += __shfl_xor(ay0, 32);
    ex0 += __shfl_xor(ex0, 32);
    ey0 += __shfl_xor(ey0, 32);
    if (!half) {
        S16[(size_t)wid * 64 + l2] = __floats2half2_rn(ax0, ay0);        // feat 2l2,2l2+1
        S16[(size_t)wid * 64 + 32 + l2] = __floats2half2_rn(ex0, ey0);   // feat 64+...
        if (lane == 0) cntRow[wid] = (float)(je - jb + 1);
    }
}

// ---------------------------------------------------------------------------
// MFMA fp16 GEMM: out = epilogue(A[N,128] @ W[128,NC]), fp32 accumulate.
// A fp16 row-major; Wt fp16 pre-transposed [NC][128]. 64 rows/block, 4 waves
// (16 rows each), mfma_f32_16x16x32_f16 over 4 K-chunks. LDS pitch 136 halves.
// Fragments (§3): A row=lane&15, k=(lane>>4)*8+j; C/D col=lane&15,
// row=(lane>>4)*4+reg. In-place safe: A tile fully staged before stores.
// MODE 0: relu(acc/cnt + b_node + (1-1/cnt)*b_edge); 1: relu(acc+b); 2: acc+b.
// ---------------------------------------------------------------------------
template <int NC, int MODE>
__global__ __launch_bounds__(256) void gemm_mfma(const __half* __restrict__ A,
                                                 const __half* __restrict__ Wt,
                                                 const float* __restrict__ ba,
                                                 const float* __restrict__ bb,
                                                 const float* __restrict__ cnt,
                                                 __half* __restrict__ out) {
    constexpr int NT = NC / 16;
    __shared__ __half Ah[64][136];
    __shared__ __half Wl[NC][136];
    const int tid = threadIdx.x;
    const int rb = blockIdx.x * 64;
    const int lane = tid & 63;
    const int wv = tid >> 6;    // wave 0..3, owns rows rb+wv*16 ..+16
    const int l15 = lane & 15;
    const int lb = lane >> 4;   // 0..3

    // stage A rows (16B/lane, coalesced)
    for (int idx = tid; idx < 64 * 16; idx += 256) {
        int r = idx >> 4, c8 = idx & 15;
        int gr = rb + r;
        uint4 v = make_uint4(0, 0, 0, 0);
        if (gr < N_NODES) v = *reinterpret_cast<const uint4*>(A + (size_t)gr * 128 + c8 * 8);
        *reinterpret_cast<uint4*>(&Ah[r][c8 * 8]) = v;
    }
    // stage Wt rows (16B/lane, coalesced)
    for (int idx = tid; idx < NC * 16; idx += 256) {
        int n = idx >> 4, c8 = idx & 15;
        uint4 v = *reinterpret_cast<const uint4*>(Wt + (size_t)n * 128 + c8 * 8);
        *reinterpret_cast<uint4*>(&Wl[n][c8 * 8]) = v;
    }
    __syncthreads();

    f16x8 af[4];
#pragma unroll
    for (int kc = 0; kc < 4; kc++)
        af[kc] = *reinterpret_cast<const f16x8*>(&Ah[wv * 16 + l15][kc * 32 + lb * 8]);

    f32x4 acc[NT];
#pragma unroll
    for (int nt = 0; nt < NT; nt++) acc[nt] = (f32x4){0.f, 0.f, 0.f, 0.f};

#pragma unroll
    for (int nt = 0; nt < NT; nt++) {
#pragma unroll
        for (int kc = 0; kc < 4; kc++) {
            f16x8 bf = *reinterpret_cast<const f16x8*>(&Wl[nt * 16 + l15][kc * 32 + lb * 8]);
            acc[nt] = __builtin_amdgcn_mfma_f32_16x16x32_f16(af[kc], bf, acc[nt], 0, 0, 0);
        }
    }

#pragma unroll
    for (int nt = 0; nt < NT; nt++) {
        int c = nt * 16 + l15;
        float bav = ba[c];
        float bbv = 0.f;
        if constexpr (MODE == 0) bbv = bb[c];
#pragma unroll
        for (int reg = 0; reg < 4; reg++) {
            int gr = rb + wv * 16 + lb * 4 + reg;
            if (gr >= N_NODES) continue;
            float v = acc[nt][reg];
            if constexpr (MODE == 0) {
                float inv = 1.0f / cnt[gr];
                v = v * inv + bav + (1.0f - inv) * bbv;
                v = fmaxf(v, 0.f);
            } else if constexpr (MODE == 1) {
                v = fmaxf(v + bav, 0.f);
            } else {
                v = v + bav;
            }
            out[(size_t)gr * NC + c] = __float2half(v);
        }
    }
}

// ---------------------------------------------------------------------------
// APPNP step (known-good): out[n] = 0.9*dinv^2*h[n] + sum w'*h[src] + 0.1*h0[n]
// ---------------------------------------------------------------------------
template <bool LAST>
__global__ __launch_bounds__(256) void appnp_step(const __half2* __restrict__ h2,
                                                  const __half2* __restrict__ h02,
                                                  void* __restrict__ outv,
                                                  const int* __restrict__ rp,
                                                  const int2* __restrict__ ew,
                                                  const float* __restrict__ dinv) {
    int wid = (blockIdx.x * 256 + threadIdx.x) >> 6;
    int lane = threadIdx.x & 63;
    if (wid >= N_NODES) return;
    int half = lane >> 5;
    int l2 = lane & 31;
    float acc0x = 0.f, acc0y = 0.f, acc1x = 0.f, acc1y = 0.f;
    if (!half) {
        float di = dinv[wid];
        float sw = (1.0f - ALPHA) * di * di;
        float2 hv = __half22float2(h2[(size_t)wid * 32 + l2]);
        acc0x = sw * hv.x; acc0y = sw * hv.y;
    }
    int e = rp[wid], eend = rp[wid + 1];
    for (; e + 3 < eend; e += 4) {
        int2 p0 = ew[e + half];
        int2 p1 = ew[e + 2 + half];
        float w0 = __int_as_float(p0.y);
        float w1 = __int_as_float(p1.y);
        float2 g0 = __half22float2(h2[(size_t)p0.x * 32 + l2]);
        float2 g1 = __half22float2(h2[(size_t)p1.x * 32 + l2]);
        acc0x += w0 * g0.x; acc0y += w0 * g0.y;
        acc1x += w1 * g1.x; acc1y += w1 * g1.y;
    }
    for (; e < eend; e += 2) {
        int ii = e + half;
        int2 p = ew[ii < eend ? ii : (eend - 1)];
        float w0 = (ii < eend) ? __int_as_float(p.y) : 0.0f;
        float2 g = __half22float2(h2[(size_t)p.x * 32 + l2]);
        acc0x += w0 * g.x; acc0y += w0 * g.y;
    }
    acc0x += acc1x; acc0y += acc1y;
    acc0x += __shfl_xor(acc0x, 32);
    acc0y += __shfl_xor(acc0y, 32);
    if (!half) {
        float2 hz = __half22float2(h02[(size_t)wid * 32 + l2]);
        float ox = acc0x + ALPHA * hz.x;
        float oy = acc0y + ALPHA * hz.y;
        if constexpr (LAST) {
            ((float2*)outv)[(size_t)wid * 32 + l2] = make_float2(ox, oy);
        } else {
            ((__half2*)outv)[(size_t)wid * 32 + l2] = __floats2half2_rn(ox, oy);
        }
    }
}

// ---------------------------------------------------------------------------
extern "C" void kernel_launch(void* const* d_in, const int* in_sizes, int n_in,
                              void* d_out, int out_size, void* d_ws, size_t ws_size,
                              hipStream_t stream) {
    const float* x      = (const float*)d_in[0];
    const float* eattr  = (const float*)d_in[1];
    const float* W_node = (const float*)d_in[2];
    const float* b_node = (const float*)d_in[3];
    const float* W_edge = (const float*)d_in[4];
    const float* b_edge = (const float*)d_in[5];
    const float* W1     = (const float*)d_in[6];
    const float* b1     = (const float*)d_in[7];
    const float* W2     = (const float*)d_in[8];
    const float* b2     = (const float*)d_in[9];
    const int*   ei     = (const int*)d_in[10];
    float* out = (float*)d_out;

    char* ws = (char*)d_ws;
    size_t off = 0;
    auto alloc = [&](size_t bytes) -> void* {
        void* p = ws + off;
        off += (bytes + 511) & ~(size_t)511;
        return p;
    };
    float*  buf0   = (float*)alloc((size_t)N_NODES * 128 * 4);   // S16; later hA16|hB16
    __half* h0_16  = (__half*)alloc((size_t)N_NODES * 64 * 2);   // also hosts ce early
    __half* x16    = (__half*)alloc((size_t)N_NODES * 64 * 2);
    int2*   ew     = (int2*)alloc((size_t)E_EDGES * 8);
    float*  cntRow = (float*)alloc((size_t)N_NODES * 4);
    int*    zeros4 = (int*)alloc((size_t)4 * N_NODES * 4);       // degRow|degDst|curRow|curDst
    float*  dinv   = (float*)alloc((size_t)N_NODES * 4);
    int*    rpRow  = (int*)alloc((size_t)(N_NODES + 1) * 4);
    int*    rpDst  = (int*)alloc((size_t)(N_NODES + 1) * 4);
    int*    blockSums = (int*)alloc(1024 * 4);
    int*    blockScan = (int*)alloc(1024 * 4);
    __half* wt0    = (__half*)alloc((size_t)128 * 128 * 2);      // [W_node;W_edge]^T fp16
    __half* wt1    = (__half*)alloc((size_t)128 * 128 * 2);      // W1^T fp16
    __half* wt2    = (__half*)alloc((size_t)64 * 128 * 2);       // W2^T fp16

    int* degRow = zeros4;
    int* degDst = zeros4 + N_NODES;
    int* curRow = zeros4 + 2 * N_NODES;
    int* curDst = zeros4 + 3 * N_NODES;

    // ce aliases the h0_16 region: dead before h0_16 is written (gemm_mfma<64,2>)
    int2* ce = (int2*)h0_16;
    __half* S16 = (__half*)buf0;

    constexpr int NB = (N_NODES + 255) / 256;  // 391 scan chunks (< 512)

    hipMemsetAsync(zeros4, 0, (size_t)4 * N_NODES * 4, stream);

    hist2<<<(E_EDGES + 255) / 256, 256, 0, stream>>>(ei, degRow, degDst);
    dinv_kernel<<<(N_NODES + 255) / 256, 256, 0, stream>>>(degDst, dinv);
    xconvert<<<(N_NODES * 32 + 255) / 256, 256, 0, stream>>>((const float2*)x, (__half2*)x16);
    wtrans<<<64, 256, 0, stream>>>(W_node, W_edge, wt0, 128);
    wtrans<<<64, 256, 0, stream>>>(W1, nullptr, wt1, 128);
    wtrans<<<32, 256, 0, stream>>>(W2, nullptr, wt2, 64);

    scan_block_sums2<<<dim3(NB, 2), 256, 0, stream>>>(degRow, degDst, blockSums);
    scan_top2<<<2, 512, 0, stream>>>(blockSums, blockScan, NB);
    scan_write_rp2<<<dim3(NB, 2), 256, 0, stream>>>(degRow, degDst, blockScan, rpRow, rpDst);

    scatter_both<<<(E_EDGES + 255) / 256, 256, 0, stream>>>(ei, dinv, rpRow, rpDst,
                                                            curRow, curDst, ce, ew);

    aggregate<<<(N_NODES + 3) / 4, 256, 0, stream>>>((const float2*)x, (const __half2*)x16,
                                                     (const float2*)eattr, rpRow, ce,
                                                     (__half2*)S16, cntRow);

    constexpr int GB = (N_NODES + 63) / 64;  // 1563 blocks
    gemm_mfma<128, 0><<<GB, 256, 0, stream>>>(S16, wt0, b_node, b_edge, cntRow, S16);
    gemm_mfma<128, 1><<<GB, 256, 0, stream>>>(S16, wt1, b1, nullptr, nullptr, S16);
    gemm_mfma<64, 2><<<GB, 256, 0, stream>>>(S16, wt2, b2, nullptr, nullptr, h0_16);

    // fp16 h double-buffers carved from buf0 (S16 dead after the GEMMs)
    __half2* hA16 = (__half2*)buf0;
    __half2* hB16 = (__half2*)(buf0 + (size_t)N_NODES * 32);  // +12.8MB
    const __half2* hcur = (const __half2*)h0_16;
    for (int k = 0; k < K_ITERS; k++) {
        if (k == K_ITERS - 1) {
            appnp_step<true><<<(N_NODES * 64 + 255) / 256, 256, 0, stream>>>(
                hcur, (const __half2*)h0_16, (void*)out, rpDst, ew, dinv);
        } else {
            __half2* dst = (k & 1) ? hB16 : hA16;
            appnp_step<false><<<(N_NODES * 64 + 255) / 256, 256, 0, stream>>>(
                hcur, (const __half2*)h0_16, (void*)dst, rpDst, ew, dinv);
            hcur = (const __half2*)dst;
        }
    }
}